// Round 3
// baseline (83970.636 us; speedup 1.0000x reference)
//
#include <hip/hip_runtime.h>

#define LSEQ 8128
#define NB 8
#define CORR_CAP 8192

typedef __attribute__((ext_vector_type(8))) short short8;
typedef __attribute__((ext_vector_type(4))) float float4e;

#define MFMA16(a, b, c) __builtin_amdgcn_mfma_f32_16x16x32_bf16((a), (b), (c), 0, 0, 0)

// ---- workspace layout (bytes) ----
#define WS_P     4096ul
#define WS_AEE   528384ul
#define WS_VPN   536576ul
#define WS_EIDX  33828864ul
#define WS_CORR  34088960ul
#define WS_H0    67643392ul
#define WS_H1    100939776ul
// total = 134236160 bytes (~134 MB)

static __device__ __forceinline__ unsigned short f2bf(float f) {
  unsigned u = __float_as_uint(f);
  return (unsigned short)((u + 0x7fffu + ((u >> 16) & 1u)) >> 16);  // RNE
}
static __device__ __forceinline__ short8 pack8f(const float* __restrict__ p) {
  short8 r;
#pragma unroll
  for (int i = 0; i < 8; ++i) r[i] = (short)f2bf(p[i]);
  return r;
}
static __device__ __forceinline__ unsigned aload(const unsigned* p) {
  return __hip_atomic_load(p, __ATOMIC_RELAXED, __HIP_MEMORY_SCOPE_AGENT);
}
static __device__ __forceinline__ void astore(unsigned* p, unsigned v) {
  __hip_atomic_store(p, v, __ATOMIC_RELAXED, __HIP_MEMORY_SCOPE_AGENT);
}
static __device__ __forceinline__ void fencev() {
  asm volatile("s_waitcnt vmcnt(0)" ::: "memory");
}
static __device__ __forceinline__ void cbar() {  // compiler-only barrier
  asm volatile("" ::: "memory");
}
static __device__ __forceinline__ float sigf(float x) { return 1.f / (1.f + __expf(-x)); }
static __device__ __forceinline__ float tanhf2(float x) { return 2.f / (1.f + __expf(-2.f * x)) - 1.f; }

// ---- P = W_ih0[:,128:192] @ ew_W2   [1024][128] ----
__global__ void k_prep_P(const float* __restrict__ Wih0, const float* __restrict__ ewW2,
                         float* __restrict__ P) {
  int idx = blockIdx.x * 256 + threadIdx.x;
  int g = idx >> 7, k = idx & 127;
  const float* wr = Wih0 + (size_t)g * 320 + 128;
  float s = 0.f;
#pragma unroll 8
  for (int j = 0; j < 64; ++j) s += wr[j] * ewW2[j * 128 + k];
  P[idx] = s;
}

__global__ void k_prep_aee_init(const float* __restrict__ Wih0, const float* __restrict__ ee,
                                const float* __restrict__ b1, const float* __restrict__ b2,
                                const float* __restrict__ P, const float* __restrict__ inith,
                                float* __restrict__ aee, unsigned short* __restrict__ h0u,
                                unsigned short* __restrict__ h1u) {
  int idx = blockIdx.x * 256 + threadIdx.x;  // < 2048
  int s = idx >> 10, g = idx & 1023;
  const float* wr = Wih0 + (size_t)g * 320;
  float a = 0.f;
#pragma unroll 8
  for (int i = 0; i < 128; ++i) a += wr[i] * ee[s * 128 + i];
#pragma unroll 8
  for (int j = 0; j < 64; ++j) a += wr[128 + j] * b2[j];
  const float* pr = P + (size_t)g * 128;
#pragma unroll 8
  for (int k = 0; k < 128; ++k) a += pr[k] * fmaxf(b1[k], 0.f);
  aee[s * 1024 + g] = a;
  unsigned short hv = f2bf(inith[idx & 127]);
  h0u[idx] = hv;
  h1u[idx] = hv;
}

__global__ void k_prep_vpn(const float* __restrict__ Wih0, const float* __restrict__ nemb,
                           const float* __restrict__ aee, float* __restrict__ vpn) {
  __shared__ float pn[128];
  int t = blockIdx.x, tid = threadIdx.x;
  if (tid < 32) {
    float div = expf(-9.2103403719761836f * (float)(2 * tid) / 64.f);
    float ang = (float)t * div;
    pn[2 * tid] = sinf(ang);
    pn[2 * tid + 1] = cosf(ang);
  } else if (tid < 96) {
    int r = (int)((1.f + sqrtf(8.f * (float)t + 1.f)) * 0.5f);
    while (r * (r + 1) / 2 <= t) ++r;
    while (r * (r - 1) / 2 > t) --r;
    pn[64 + (tid - 32)] = nemb[r * 64 + (tid - 32)];
  }
  __syncthreads();
#pragma unroll
  for (int rr = 0; rr < 4; ++rr) {
    int row = rr * 256 + tid;
    const float* wr = Wih0 + (size_t)row * 320 + 192;
    float s = 0.f;
#pragma unroll 8
    for (int i = 0; i < 128; ++i) s += wr[i] * pn[i];
    vpn[(size_t)t * 1024 + row] = s + aee[row];
  }
}

__global__ void k_prep_eidx(const float* __restrict__ xadj, int* __restrict__ eidx,
                            unsigned* __restrict__ counter) {
  int idx = blockIdx.x * 256 + threadIdx.x;
  if (idx >= NB * LSEQ) return;
  int t = idx % LSEQ;
  int e = -1;
  if (t > 0 && xadj[idx - 1] > 0.f) {
    e = (int)atomicAdd(counter, 1u);
    if (e >= CORR_CAP) e = -1;
  }
  eidx[idx] = e;
}

__global__ void k_prep_corr(const float* __restrict__ xadj, const float* __restrict__ w1,
                            const float* __restrict__ b1, const float* __restrict__ P,
                            const float* __restrict__ aee, const int* __restrict__ eidx,
                            float* __restrict__ corr) {
  __shared__ float rh[128];
  int bid = blockIdx.x;
  int e = eidx[bid];
  if (e < 0) return;
  int tid = threadIdx.x;
  float wt = xadj[bid - 1];
  if (tid < 128) {
    float bb = b1[tid];
    rh[tid] = fmaxf(wt * w1[tid] + bb, 0.f) - fmaxf(bb, 0.f);
  }
  __syncthreads();
#pragma unroll
  for (int rr = 0; rr < 4; ++rr) {
    int row = rr * 256 + tid;
    const float* pr = P + (size_t)row * 128;
    float s = 0.f;
#pragma unroll 8
    for (int k = 0; k < 128; ++k) s += pr[k] * rh[k];
    corr[(size_t)e * 1024 + row] = s + aee[1024 + row] - aee[row];
  }
}

// ---- persistent 2-layer LSTM scan: blocks 0-1 = layer0 halves, 2-5 = layer1 quarters ----
// Cross-WG exchange: agent-scope RELAXED atomics only (serviced at device coherence
// point -> no cache-invalidate fences needed). Ordering: s_waitcnt vmcnt(0) +
// __syncthreads before flag publication; compiler barriers after flag spins.
// Every spin has a shared exhaustible budget so a protocol bug cannot hang.
__global__ __launch_bounds__(512, 2) void k_lstm(
    const float* __restrict__ Whh0, const float* __restrict__ Wih1,
    const float* __restrict__ Whh1, const float* __restrict__ vpn,
    const int* __restrict__ eidx, const float* __restrict__ corr,
    const float* __restrict__ inith, const float* __restrict__ initc,
    unsigned* flags, unsigned* h0w, unsigned* h1w) {
  __shared__ __align__(16) unsigned short hT[16 * 264];
  __shared__ __align__(16) unsigned short hU[16 * 264];
  __shared__ __align__(16) float gbuf[8 * 4 * 128];
  __shared__ __align__(16) float cbuf[8 * 128];

  const int tid = threadIdx.x;
  const int bx = blockIdx.x;
  const bool isL0 = (bx < 2);
  const int W = isL0 ? bx : 0;
  const int Q = isL0 ? 0 : (bx - 2);
  const int v = tid >> 6, l = tid & 63, lm = l & 15, lk = l >> 4;
  unsigned budget = 50000000u;  // shared spin budget: deadlock -> fast wrong exit

  for (int i = tid; i < 16 * 264; i += 512) { hT[i] = 0; hU[i] = 0; }
  __syncthreads();
  for (int i = tid; i < 2048; i += 512) {
    int b = i >> 8, j = i & 255;
    unsigned short hv = f2bf(inith[j & 127]);
    if (isL0) hT[b * 264 + j] = hv; else hU[b * 264 + j] = hv;
  }
  if (isL0) {
    for (int i = tid; i < 1024; i += 512) { int j = i & 127; cbuf[i] = initc[j]; }
  } else {
    int b = tid >> 6, j = tid & 63;
    cbuf[b * 128 + j] = initc[(Q * 64 + j) & 127];
  }

  // recurrent weights as bf16 A-fragments in registers
  short8 wf[32];
  if (isL0) {
#pragma unroll
    for (int tt = 0; tt < 4; ++tt) {
      int ft = v * 4 + tt, gate = ft >> 3, jb = ft & 7;
      int row = gate * 256 + W * 128 + jb * 16 + lm;
#pragma unroll
      for (int ks = 0; ks < 8; ++ks)
        wf[tt * 8 + ks] = pack8f(Whh0 + (size_t)row * 256 + ks * 32 + lk * 8);
    }
  } else {
#pragma unroll
    for (int tt = 0; tt < 2; ++tt) {
      int ft = v * 2 + tt, gate = ft >> 2, jb = ft & 3;
      int row = gate * 256 + Q * 64 + jb * 16 + lm;
#pragma unroll
      for (int ks = 0; ks < 16; ++ks) {
        int k = ks * 32 + lk * 8;
        const float* src = (k < 256) ? (Wih1 + (size_t)row * 256 + k)
                                     : (Whh1 + (size_t)row * 256 + (k - 256));
        wf[tt * 16 + ks] = pack8f(src);
      }
    }
  }
  __syncthreads();

  for (int t = 0; t < LSEQ; ++t) {
    if (isL0) {
      const int peer = 1 - W;
      // ---- pre-wait: acc init + own-half MFMAs (peer-independent) ----
      int bc = (lm < 8) ? lm : 0;
      int e = eidx[bc * LSEQ + t];
      short8 bown[4];
#pragma unroll
      for (int ks = 0; ks < 4; ++ks)
        bown[ks] = *(const short8*)(hT + lm * 264 + (W * 4 + ks) * 32 + lk * 8);
      float4e acc[4];
#pragma unroll
      for (int tt = 0; tt < 4; ++tt) {
        int ft = v * 4 + tt, gate = ft >> 3, jb = ft & 7;
        int rowb = gate * 256 + W * 128 + jb * 16;
        float4e cv = *(const float4e*)(vpn + (size_t)t * 1024 + rowb + lk * 4);
        if (e >= 0) cv += *(const float4e*)(corr + (size_t)e * 1024 + rowb + lk * 4);
#pragma unroll
        for (int ks = 0; ks < 4; ++ks) cv = MFMA16(wf[tt * 8 + W * 4 + ks], bown[ks], cv);
        acc[tt] = cv;
      }
      // ---- wait peer, stage its half, finish MFMAs ----
      while (true) {
        unsigned f = aload(flags + peer);
        if (__all((int)(f >= (unsigned)t)) | (budget == 0)) break;
        --budget;
      }
      cbar();
      {
        int b = tid >> 6, wo = tid & 63;
        unsigned wd = aload(h0w + (size_t)t * 1024 + b * 128 + peer * 64 + wo);
        ((unsigned*)hT)[b * 132 + peer * 64 + wo] = wd;
      }
      __syncthreads();
#pragma unroll
      for (int ks = 0; ks < 4; ++ks) {
        short8 bp = *(const short8*)(hT + lm * 264 + (peer * 4 + ks) * 32 + lk * 8);
#pragma unroll
        for (int tt = 0; tt < 4; ++tt) acc[tt] = MFMA16(wf[tt * 8 + peer * 4 + ks], bp, acc[tt]);
      }
      if (lm < 8) {
#pragma unroll
        for (int tt = 0; tt < 4; ++tt) {
          int ft = v * 4 + tt, gate = ft >> 3, jb = ft & 7;
#pragma unroll
          for (int r = 0; r < 4; ++r)
            gbuf[(lm * 4 + gate) * 128 + jb * 16 + lk * 4 + r] = acc[tt][r];
        }
      }
      __syncthreads();
      {
        int b = tid >> 6, jp = tid & 63;
        float h2[2];
#pragma unroll
        for (int s2 = 0; s2 < 2; ++s2) {
          int j = jp * 2 + s2;
          float gi = gbuf[(b * 4 + 0) * 128 + j];
          float gf = gbuf[(b * 4 + 1) * 128 + j];
          float gg = gbuf[(b * 4 + 2) * 128 + j];
          float go = gbuf[(b * 4 + 3) * 128 + j];
          float c = cbuf[b * 128 + j];
          c = sigf(gf) * c + sigf(gi) * tanhf2(gg);
          cbuf[b * 128 + j] = c;
          h2[s2] = sigf(go) * tanhf2(c);
        }
        unsigned wd = (unsigned)f2bf(h2[0]) | ((unsigned)f2bf(h2[1]) << 16);
        ((unsigned*)hT)[b * 132 + W * 64 + jp] = wd;
        astore(h0w + (size_t)(t + 1) * 1024 + b * 128 + W * 64 + jp, wd);
      }
      fencev();
      __syncthreads();
      if (tid == 0) astore(flags + W, (unsigned)(t + 1));
    } else {
      // ---- phase A: wait L1 peers' h1(t-1), MFMA over the h1 half of K ----
      while (true) {
        bool ok = true;
        if (l < 4) ok = (aload(flags + 2 + l) >= (unsigned)t);
        if (__all((int)ok) | (budget == 0)) break;
        --budget;
      }
      cbar();
      for (int i = tid; i < 768; i += 512) {
        int pi = i >> 8, rem = i & 255;
        int b = rem >> 5, wo = rem & 31;
        int p = pi + (pi >= Q ? 1 : 0);
        unsigned wd = aload(h1w + (size_t)t * 1024 + b * 128 + p * 32 + wo);
        ((unsigned*)hU)[b * 132 + p * 32 + wo] = wd;
      }
      __syncthreads();
      float4e a0 = {0.f, 0.f, 0.f, 0.f}, a1 = {0.f, 0.f, 0.f, 0.f};
#pragma unroll
      for (int ks = 8; ks < 16; ++ks) {
        short8 bfr = *(const short8*)(hU + lm * 264 + (ks - 8) * 32 + lk * 8);
        a0 = MFMA16(wf[ks], bfr, a0);
        a1 = MFMA16(wf[16 + ks], bfr, a1);
      }
      // ---- phase B: wait L0 step t done, stage h0(t), MFMA over the h0 half ----
      while (true) {
        bool ok = true;
        if (l < 2) ok = (aload(flags + l) >= (unsigned)(t + 1));
        if (__all((int)ok) | (budget == 0)) break;
        --budget;
      }
      cbar();
      {
        const unsigned* s0 = h0w + (size_t)(t + 1) * 1024 + tid;
        unsigned w0 = aload(s0);
        unsigned w1 = aload(s0 + 512);
        int i1 = tid + 512;
        ((unsigned*)hT)[(tid >> 7) * 132 + (tid & 127)] = w0;
        ((unsigned*)hT)[(i1 >> 7) * 132 + (i1 & 127)] = w1;
      }
      __syncthreads();
#pragma unroll
      for (int ks = 0; ks < 8; ++ks) {
        short8 bfr = *(const short8*)(hT + lm * 264 + ks * 32 + lk * 8);
        a0 = MFMA16(wf[ks], bfr, a0);
        a1 = MFMA16(wf[16 + ks], bfr, a1);
      }
      if (lm < 8) {
#pragma unroll
        for (int tt = 0; tt < 2; ++tt) {
          float4e av = tt ? a1 : a0;
          int ft = v * 2 + tt, gate = ft >> 2, jb = ft & 3;
#pragma unroll
          for (int r = 0; r < 4; ++r)
            gbuf[(lm * 4 + gate) * 64 + jb * 16 + lk * 4 + r] = av[r];
        }
      }
      __syncthreads();
      if (tid < 256) {
        int b = tid >> 5, jp = tid & 31;
        float h2[2];
#pragma unroll
        for (int s2 = 0; s2 < 2; ++s2) {
          int j = jp * 2 + s2;
          float gi = gbuf[(b * 4 + 0) * 64 + j];
          float gf = gbuf[(b * 4 + 1) * 64 + j];
          float gg = gbuf[(b * 4 + 2) * 64 + j];
          float go = gbuf[(b * 4 + 3) * 64 + j];
          float c = cbuf[b * 128 + j];
          c = sigf(gf) * c + sigf(gi) * tanhf2(gg);
          cbuf[b * 128 + j] = c;
          h2[s2] = sigf(go) * tanhf2(c);
        }
        unsigned wd = (unsigned)f2bf(h2[0]) | ((unsigned)f2bf(h2[1]) << 16);
        ((unsigned*)hU)[b * 132 + Q * 32 + jp] = wd;
        astore(h1w + (size_t)(t + 1) * 1024 + b * 128 + Q * 32 + jp, wd);
      }
      fencev();
      __syncthreads();
      if (tid == 0) astore(flags + 2 + Q, (unsigned)(t + 1));
    }
  }
}

// ---- heads: 3x (256->512 relu ->1) via MFMA, then BCE + Gaussian NLL reduction ----
__global__ __launch_bounds__(256, 2) void k_heads(
    const unsigned short* __restrict__ h1u, const float* __restrict__ xadj,
    const float* __restrict__ lgW1, const float* __restrict__ lgb1,
    const float* __restrict__ lgW2, const float* __restrict__ lgb2,
    const float* __restrict__ muW1, const float* __restrict__ mub1,
    const float* __restrict__ muW2, const float* __restrict__ mub2,
    const float* __restrict__ vaW1, const float* __restrict__ vab1,
    const float* __restrict__ vaW2, const float* __restrict__ vab2,
    float* dout) {
  __shared__ float vals[4][3][64];
  const int tid = threadIdx.x;
  const int v = tid >> 6, l = tid & 63, lm = l & 15, lk = l >> 4;
  const int wid = blockIdx.x * 4 + v;
  const int m0 = wid * 64;

  short8 afr[4][8];
#pragma unroll
  for (int tt = 0; tt < 4; ++tt)
#pragma unroll
    for (int ks = 0; ks < 8; ++ks)
      afr[tt][ks] = *(const short8*)(h1u + (size_t)(m0 + tt * 16 + lm) * 256 + 2048 + ks * 32 + lk * 8);

  const float* W1s[3] = {lgW1, muW1, vaW1};
  const float* b1s[3] = {lgb1, mub1, vab1};
  const float* W2s[3] = {lgW2, muW2, vaW2};

  for (int h = 0; h < 3; ++h) {
    float accr[4][4];
#pragma unroll
    for (int tt = 0; tt < 4; ++tt)
#pragma unroll
      for (int r = 0; r < 4; ++r) accr[tt][r] = 0.f;
    const float* W1p = W1s[h];
    const float* b1p = b1s[h];
    const float* W2p = W2s[h];
    for (int nt = 0; nt < 32; ++nt) {
      float4e c0 = {0.f, 0.f, 0.f, 0.f}, c1 = c0, c2 = c0, c3 = c0;
      const float* wp = W1p + (size_t)(nt * 16 + lm) * 256;
#pragma unroll
      for (int ks = 0; ks < 8; ++ks) {
        short8 bfr = pack8f(wp + ks * 32 + lk * 8);
        c0 = MFMA16(afr[0][ks], bfr, c0);
        c1 = MFMA16(afr[1][ks], bfr, c1);
        c2 = MFMA16(afr[2][ks], bfr, c2);
        c3 = MFMA16(afr[3][ks], bfr, c3);
      }
      float bias = b1p[nt * 16 + lm], w2v = W2p[nt * 16 + lm];
#pragma unroll
      for (int r = 0; r < 4; ++r) {
        accr[0][r] += fmaxf(c0[r] + bias, 0.f) * w2v;
        accr[1][r] += fmaxf(c1[r] + bias, 0.f) * w2v;
        accr[2][r] += fmaxf(c2[r] + bias, 0.f) * w2v;
        accr[3][r] += fmaxf(c3[r] + bias, 0.f) * w2v;
      }
    }
#pragma unroll
    for (int tt = 0; tt < 4; ++tt)
#pragma unroll
      for (int r = 0; r < 4; ++r) {
        float a2 = accr[tt][r];
        a2 += __shfl_xor(a2, 1);
        a2 += __shfl_xor(a2, 2);
        a2 += __shfl_xor(a2, 4);
        a2 += __shfl_xor(a2, 8);
        if (lm == 0) vals[v][h][tt * 16 + lk * 4 + r] = a2;
      }
  }
  __syncthreads();
  {
    int m = m0 + l;
    int tq = m >> 3, b = m & 7;
    float z = vals[v][0][l] + lgb2[0];
    float mu = vals[v][1][l] + mub2[0];
    float lv = vals[v][2][l] + vab2[0];
    float x = xadj[(size_t)b * LSEQ + tq];
    float xt = (x > 0.f) ? 1.f : 0.f;
    float lr = fmaxf(z, 0.f) - z * xt + log1pf(expf(-fabsf(z)));
    float lw = 0.f;
    if (x > 0.f) {
      float sm = (x > 20.f) ? x : logf(expm1f(fminf(x, 20.f)));
      float d = mu - sm;
      lw = 0.5f * (lv + d * d * expf(-lv));
    }
#pragma unroll
    for (int d2 = 1; d2 < 64; d2 <<= 1) {
      lr += __shfl_xor(lr, d2);
      lw += __shfl_xor(lw, d2);
    }
    if (l == 0) {
      atomicAdd(dout + 0, lr * (1.f / 1024.f));
      atomicAdd(dout + 1, lw * (1.f / 1024.f));
    }
  }
}

extern "C" void kernel_launch(void* const* d_in, const int* in_sizes, int n_in,
                              void* d_out, int out_size, void* d_ws, size_t ws_size,
                              hipStream_t stream) {
  const float* x_adj = (const float*)d_in[0];
  const float* ee    = (const float*)d_in[1];
  const float* nemb  = (const float*)d_in[2];
  const float* ewW1  = (const float*)d_in[3];
  const float* ewb1  = (const float*)d_in[4];
  const float* ewW2  = (const float*)d_in[5];
  const float* ewb2  = (const float*)d_in[6];
  const float* Wih0  = (const float*)d_in[7];
  const float* Whh0  = (const float*)d_in[8];
  const float* Wih1  = (const float*)d_in[9];
  const float* Whh1  = (const float*)d_in[10];
  const float* muW1  = (const float*)d_in[11];
  const float* mub1  = (const float*)d_in[12];
  const float* muW2  = (const float*)d_in[13];
  const float* mub2  = (const float*)d_in[14];
  const float* vaW1  = (const float*)d_in[15];
  const float* vab1  = (const float*)d_in[16];
  const float* vaW2  = (const float*)d_in[17];
  const float* vab2  = (const float*)d_in[18];
  const float* lgW1  = (const float*)d_in[19];
  const float* lgb1  = (const float*)d_in[20];
  const float* lgW2  = (const float*)d_in[21];
  const float* lgb2  = (const float*)d_in[22];
  const float* inith = (const float*)d_in[23];
  const float* initc = (const float*)d_in[24];

  char* wsb = (char*)d_ws;
  unsigned* flags    = (unsigned*)wsb;            // 6 words
  unsigned* counter  = (unsigned*)(wsb + 64);
  float* P           = (float*)(wsb + WS_P);
  float* aee         = (float*)(wsb + WS_AEE);
  float* vpn         = (float*)(wsb + WS_VPN);
  int* eidx          = (int*)(wsb + WS_EIDX);
  float* corr        = (float*)(wsb + WS_CORR);
  unsigned* h0w      = (unsigned*)(wsb + WS_H0);
  unsigned* h1w      = (unsigned*)(wsb + WS_H1);
  unsigned short* h0u = (unsigned short*)(wsb + WS_H0);
  unsigned short* h1u = (unsigned short*)(wsb + WS_H1);

  (void)in_sizes; (void)n_in; (void)ws_size;

  hipMemsetAsync(d_ws, 0, 4096, stream);
  hipMemsetAsync(d_out, 0, (size_t)out_size * 4, stream);

  k_prep_P<<<512, 256, 0, stream>>>(Wih0, ewW2, P);
  k_prep_aee_init<<<8, 256, 0, stream>>>(Wih0, ee, ewb1, ewb2, P, inith, aee, h0u, h1u);
  k_prep_vpn<<<LSEQ, 256, 0, stream>>>(Wih0, nemb, aee, vpn);
  k_prep_eidx<<<(NB * LSEQ) / 256, 256, 0, stream>>>(x_adj, eidx, counter);
  k_prep_corr<<<NB * LSEQ, 256, 0, stream>>>(x_adj, ewW1, ewb1, P, aee, eidx, corr);
  k_lstm<<<6, 512, 0, stream>>>(Whh0, Wih1, Whh1, vpn, eidx, corr, inith, initc,
                                flags, h0w, h1w);
  k_heads<<<254, 256, 0, stream>>>(h1u, x_adj, lgW1, lgb1, lgW2, lgb2,
                                   muW1, mub1, muW2, mub2, vaW1, vab1, vaW2, vab2,
                                   (float*)d_out);
}

// Round 4
// 31851.617 us; speedup vs baseline: 2.6363x; 2.6363x over previous
//
#include <hip/hip_runtime.h>

#define LSEQ 8128
#define NB 8
#define CORR_CAP 8192

typedef __attribute__((ext_vector_type(8))) short short8;
typedef __attribute__((ext_vector_type(4))) float float4e;

#define MFMA16(a, b, c) __builtin_amdgcn_mfma_f32_16x16x32_bf16((a), (b), (c), 0, 0, 0)

// ---- workspace layout (bytes) ----
#define WS_P     4096ul
#define WS_AEE   528384ul
#define WS_VPN   536576ul
#define WS_EIDX  33828864ul
#define WS_CORR  34088960ul
#define WS_H0    67643392ul
#define WS_H1    100939776ul
// total = 134236160 bytes (~134 MB)

static __device__ __forceinline__ unsigned short f2bf(float f) {
  unsigned u = __float_as_uint(f);
  return (unsigned short)((u + 0x7fffu + ((u >> 16) & 1u)) >> 16);  // RNE
}
static __device__ __forceinline__ short8 pack8f(const float* __restrict__ p) {
  short8 r;
#pragma unroll
  for (int i = 0; i < 8; ++i) r[i] = (short)f2bf(p[i]);
  return r;
}
static __device__ __forceinline__ unsigned aload(const unsigned* p) {
  return __hip_atomic_load(p, __ATOMIC_RELAXED, __HIP_MEMORY_SCOPE_AGENT);
}
static __device__ __forceinline__ void astore(unsigned* p, unsigned v) {
  __hip_atomic_store(p, v, __ATOMIC_RELAXED, __HIP_MEMORY_SCOPE_AGENT);
}
static __device__ __forceinline__ void fencev() {
  asm volatile("s_waitcnt vmcnt(0)" ::: "memory");
}
static __device__ __forceinline__ void cbar() {
  asm volatile("" ::: "memory");
}
static __device__ __forceinline__ float sigf(float x) { return 1.f / (1.f + __expf(-x)); }
static __device__ __forceinline__ float tanhf2(float x) { return 2.f / (1.f + __expf(-2.f * x)) - 1.f; }

// ---- P = W_ih0[:,128:192] @ ew_W2   [1024][128] ----
__global__ void k_prep_P(const float* __restrict__ Wih0, const float* __restrict__ ewW2,
                         float* __restrict__ P) {
  int idx = blockIdx.x * 256 + threadIdx.x;
  int g = idx >> 7, k = idx & 127;
  const float* wr = Wih0 + (size_t)g * 320 + 128;
  float s = 0.f;
#pragma unroll 8
  for (int j = 0; j < 64; ++j) s += wr[j] * ewW2[j * 128 + k];
  P[idx] = s;
}

__global__ void k_prep_aee_init(const float* __restrict__ Wih0, const float* __restrict__ ee,
                                const float* __restrict__ b1, const float* __restrict__ b2,
                                const float* __restrict__ P, const float* __restrict__ inith,
                                float* __restrict__ aee, unsigned short* __restrict__ h0u,
                                unsigned short* __restrict__ h1u) {
  int idx = blockIdx.x * 256 + threadIdx.x;  // < 2048
  int s = idx >> 10, g = idx & 1023;
  const float* wr = Wih0 + (size_t)g * 320;
  float a = 0.f;
#pragma unroll 8
  for (int i = 0; i < 128; ++i) a += wr[i] * ee[s * 128 + i];
#pragma unroll 8
  for (int j = 0; j < 64; ++j) a += wr[128 + j] * b2[j];
  const float* pr = P + (size_t)g * 128;
#pragma unroll 8
  for (int k = 0; k < 128; ++k) a += pr[k] * fmaxf(b1[k], 0.f);
  aee[s * 1024 + g] = a;
  unsigned short hv = f2bf(inith[idx & 127]);
  h0u[idx] = hv;
  h1u[idx] = hv;
}

__global__ void k_prep_vpn(const float* __restrict__ Wih0, const float* __restrict__ nemb,
                           const float* __restrict__ aee, float* __restrict__ vpn) {
  __shared__ float pn[128];
  int t = blockIdx.x, tid = threadIdx.x;
  if (tid < 32) {
    float div = expf(-9.2103403719761836f * (float)(2 * tid) / 64.f);
    float ang = (float)t * div;
    pn[2 * tid] = sinf(ang);
    pn[2 * tid + 1] = cosf(ang);
  } else if (tid < 96) {
    int r = (int)((1.f + sqrtf(8.f * (float)t + 1.f)) * 0.5f);
    while (r * (r + 1) / 2 <= t) ++r;
    while (r * (r - 1) / 2 > t) --r;
    pn[64 + (tid - 32)] = nemb[r * 64 + (tid - 32)];
  }
  __syncthreads();
#pragma unroll
  for (int rr = 0; rr < 4; ++rr) {
    int row = rr * 256 + tid;
    const float* wr = Wih0 + (size_t)row * 320 + 192;
    float s = 0.f;
#pragma unroll 8
    for (int i = 0; i < 128; ++i) s += wr[i] * pn[i];
    vpn[(size_t)t * 1024 + row] = s + aee[row];
  }
}

__global__ void k_prep_eidx(const float* __restrict__ xadj, int* __restrict__ eidx,
                            unsigned* __restrict__ counter) {
  int idx = blockIdx.x * 256 + threadIdx.x;
  if (idx >= NB * LSEQ) return;
  int t = idx % LSEQ;
  int e = -1;
  if (t > 0 && xadj[idx - 1] > 0.f) {
    e = (int)atomicAdd(counter, 1u);
    if (e >= CORR_CAP) e = -1;
  }
  eidx[idx] = e;
}

__global__ void k_prep_corr(const float* __restrict__ xadj, const float* __restrict__ w1,
                            const float* __restrict__ b1, const float* __restrict__ P,
                            const float* __restrict__ aee, const int* __restrict__ eidx,
                            float* __restrict__ corr) {
  __shared__ float rh[128];
  int bid = blockIdx.x;
  int e = eidx[bid];
  if (e < 0) return;
  int tid = threadIdx.x;
  float wt = xadj[bid - 1];
  if (tid < 128) {
    float bb = b1[tid];
    rh[tid] = fmaxf(wt * w1[tid] + bb, 0.f) - fmaxf(bb, 0.f);
  }
  __syncthreads();
#pragma unroll
  for (int rr = 0; rr < 4; ++rr) {
    int row = rr * 256 + tid;
    const float* pr = P + (size_t)row * 128;
    float s = 0.f;
#pragma unroll 8
    for (int k = 0; k < 128; ++k) s += pr[k] * rh[k];
    corr[(size_t)e * 1024 + row] = s + aee[1024 + row] - aee[row];
  }
}

// ================= persistent LSTM scan =================
// L0 role templated on W so ALL wf indices are compile-time constants
// (runtime indexing demoted wf to scratch in R3: VGPR 128->72, 3x slower).

template <int W>
static __device__ __forceinline__ void l0_loop(
    const float* __restrict__ Whh0, const float* __restrict__ vpn,
    const int* __restrict__ eidx, const float* __restrict__ corr,
    const float* __restrict__ inith, const float* __restrict__ initc,
    unsigned* flags, unsigned* h0w,
    unsigned short* hT, float* gbuf, float* cbuf, int tid) {
  constexpr int peer = 1 - W;
  const int v = tid >> 6, l = tid & 63, lm = l & 15, lk = l >> 4;
  unsigned budget = 50000000u;

  for (int i = tid; i < 16 * 264; i += 512) hT[i] = 0;
  __syncthreads();
  for (int i = tid; i < 2048; i += 512) {
    int b = i >> 8, j = i & 255;
    hT[b * 264 + j] = f2bf(inith[j & 127]);
  }
  for (int i = tid; i < 1024; i += 512) cbuf[i] = initc[i & 127];

  short8 wf[32];
#pragma unroll
  for (int tt = 0; tt < 4; ++tt) {
    int ft = v * 4 + tt, gate = ft >> 3, jb = ft & 7;
    int row = gate * 256 + W * 128 + jb * 16 + lm;
#pragma unroll
    for (int ks = 0; ks < 8; ++ks)
      wf[tt * 8 + ks] = pack8f(Whh0 + (size_t)row * 256 + ks * 32 + lk * 8);
  }
  __syncthreads();

  for (int t = 0; t < LSEQ; ++t) {
    // ---- pre-wait: acc init + own-half MFMAs (peer-independent) ----
    int bc = (lm < 8) ? lm : 0;
    int e = eidx[bc * LSEQ + t];
    short8 bown[4];
#pragma unroll
    for (int ks = 0; ks < 4; ++ks)
      bown[ks] = *(const short8*)(hT + lm * 264 + (W * 4 + ks) * 32 + lk * 8);
    float4e acc[4];
#pragma unroll
    for (int tt = 0; tt < 4; ++tt) {
      int ft = v * 4 + tt, gate = ft >> 3, jb = ft & 7;
      int rowb = gate * 256 + W * 128 + jb * 16;
      float4e cv = *(const float4e*)(vpn + (size_t)t * 1024 + rowb + lk * 4);
      if (e >= 0) cv += *(const float4e*)(corr + (size_t)e * 1024 + rowb + lk * 4);
#pragma unroll
      for (int ks = 0; ks < 4; ++ks) cv = MFMA16(wf[tt * 8 + W * 4 + ks], bown[ks], cv);
      acc[tt] = cv;
    }
    // ---- wait peer, stage its half, finish MFMAs ----
    while (true) {
      unsigned f = aload(flags + peer);
      if (__all((int)(f >= (unsigned)t)) | (budget == 0)) break;
      --budget;
    }
    cbar();
    {
      int b = tid >> 6, wo = tid & 63;
      unsigned wd = aload(h0w + (size_t)t * 1024 + b * 128 + peer * 64 + wo);
      ((unsigned*)hT)[b * 132 + peer * 64 + wo] = wd;
    }
    __syncthreads();
#pragma unroll
    for (int ks = 0; ks < 4; ++ks) {
      short8 bp = *(const short8*)(hT + lm * 264 + (peer * 4 + ks) * 32 + lk * 8);
#pragma unroll
      for (int tt = 0; tt < 4; ++tt) acc[tt] = MFMA16(wf[tt * 8 + peer * 4 + ks], bp, acc[tt]);
    }
    if (lm < 8) {
#pragma unroll
      for (int tt = 0; tt < 4; ++tt) {
        int ft = v * 4 + tt, gate = ft >> 3, jb = ft & 7;
#pragma unroll
        for (int r = 0; r < 4; ++r)
          gbuf[(lm * 4 + gate) * 128 + jb * 16 + lk * 4 + r] = acc[tt][r];
      }
    }
    __syncthreads();
    {
      int b = tid >> 6, jp = tid & 63;
      float h2[2];
#pragma unroll
      for (int s2 = 0; s2 < 2; ++s2) {
        int j = jp * 2 + s2;
        float gi = gbuf[(b * 4 + 0) * 128 + j];
        float gf = gbuf[(b * 4 + 1) * 128 + j];
        float gg = gbuf[(b * 4 + 2) * 128 + j];
        float go = gbuf[(b * 4 + 3) * 128 + j];
        float c = cbuf[b * 128 + j];
        c = sigf(gf) * c + sigf(gi) * tanhf2(gg);
        cbuf[b * 128 + j] = c;
        h2[s2] = sigf(go) * tanhf2(c);
      }
      unsigned wd = (unsigned)f2bf(h2[0]) | ((unsigned)f2bf(h2[1]) << 16);
      ((unsigned*)hT)[b * 132 + W * 64 + jp] = wd;
      astore(h0w + (size_t)(t + 1) * 1024 + b * 128 + W * 64 + jp, wd);
    }
    fencev();
    __syncthreads();
    if (tid == 0) astore(flags + W, (unsigned)(t + 1));
  }
}

static __device__ __forceinline__ void l1_loop(
    int Q, const float* __restrict__ Wih1, const float* __restrict__ Whh1,
    const float* __restrict__ inith, const float* __restrict__ initc,
    unsigned* flags, unsigned* h0w, unsigned* h1w,
    unsigned short* hT, unsigned short* hU, float* gbuf, float* cbuf, int tid) {
  const int v = tid >> 6, l = tid & 63, lm = l & 15, lk = l >> 4;
  unsigned budget = 50000000u;

  for (int i = tid; i < 16 * 264; i += 512) { hT[i] = 0; hU[i] = 0; }
  __syncthreads();
  for (int i = tid; i < 2048; i += 512) {
    int b = i >> 8, j = i & 255;
    hU[b * 264 + j] = f2bf(inith[j & 127]);
  }
  {
    int b = tid >> 6, j = tid & 63;
    cbuf[b * 128 + j] = initc[(Q * 64 + j) & 127];
  }

  short8 wf[32];
#pragma unroll
  for (int tt = 0; tt < 2; ++tt) {
    int ft = v * 2 + tt, gate = ft >> 2, jb = ft & 3;
    int row = gate * 256 + Q * 64 + jb * 16 + lm;
#pragma unroll
    for (int ks = 0; ks < 16; ++ks) {
      int k = ks * 32 + lk * 8;
      const float* src = (k < 256) ? (Wih1 + (size_t)row * 256 + k)
                                   : (Whh1 + (size_t)row * 256 + (k - 256));
      wf[tt * 16 + ks] = pack8f(src);
    }
  }
  __syncthreads();

  for (int t = 0; t < LSEQ; ++t) {
    // ---- phase A: wait L1 peers' h1(t-1), MFMA over the h1 half of K ----
    while (true) {
      bool ok = true;
      if (l < 4) ok = (aload(flags + 2 + l) >= (unsigned)t);
      if (__all((int)ok) | (budget == 0)) break;
      --budget;
    }
    cbar();
    for (int i = tid; i < 768; i += 512) {
      int pi = i >> 8, rem = i & 255;
      int b = rem >> 5, wo = rem & 31;
      int p = pi + (pi >= Q ? 1 : 0);
      unsigned wd = aload(h1w + (size_t)t * 1024 + b * 128 + p * 32 + wo);
      ((unsigned*)hU)[b * 132 + p * 32 + wo] = wd;
    }
    __syncthreads();
    float4e a0 = {0.f, 0.f, 0.f, 0.f}, a1 = {0.f, 0.f, 0.f, 0.f};
#pragma unroll
    for (int ks = 8; ks < 16; ++ks) {
      short8 bfr = *(const short8*)(hU + lm * 264 + (ks - 8) * 32 + lk * 8);
      a0 = MFMA16(wf[ks], bfr, a0);
      a1 = MFMA16(wf[16 + ks], bfr, a1);
    }
    // ---- phase B: wait L0 step t done, stage h0(t), MFMA over the h0 half ----
    while (true) {
      bool ok = true;
      if (l < 2) ok = (aload(flags + l) >= (unsigned)(t + 1));
      if (__all((int)ok) | (budget == 0)) break;
      --budget;
    }
    cbar();
    {
      const unsigned* s0 = h0w + (size_t)(t + 1) * 1024 + tid;
      unsigned w0 = aload(s0);
      unsigned w1 = aload(s0 + 512);
      int i1 = tid + 512;
      ((unsigned*)hT)[(tid >> 7) * 132 + (tid & 127)] = w0;
      ((unsigned*)hT)[(i1 >> 7) * 132 + (i1 & 127)] = w1;
    }
    __syncthreads();
#pragma unroll
    for (int ks = 0; ks < 8; ++ks) {
      short8 bfr = *(const short8*)(hT + lm * 264 + ks * 32 + lk * 8);
      a0 = MFMA16(wf[ks], bfr, a0);
      a1 = MFMA16(wf[16 + ks], bfr, a1);
    }
    if (lm < 8) {
#pragma unroll
      for (int tt = 0; tt < 2; ++tt) {
        float4e av = tt ? a1 : a0;
        int ft = v * 2 + tt, gate = ft >> 2, jb = ft & 3;
#pragma unroll
        for (int r = 0; r < 4; ++r)
          gbuf[(lm * 4 + gate) * 64 + jb * 16 + lk * 4 + r] = av[r];
      }
    }
    __syncthreads();
    if (tid < 256) {
      int b = tid >> 5, jp = tid & 31;
      float h2[2];
#pragma unroll
      for (int s2 = 0; s2 < 2; ++s2) {
        int j = jp * 2 + s2;
        float gi = gbuf[(b * 4 + 0) * 64 + j];
        float gf = gbuf[(b * 4 + 1) * 64 + j];
        float gg = gbuf[(b * 4 + 2) * 64 + j];
        float go = gbuf[(b * 4 + 3) * 64 + j];
        float c = cbuf[b * 128 + j];
        c = sigf(gf) * c + sigf(gi) * tanhf2(gg);
        cbuf[b * 128 + j] = c;
        h2[s2] = sigf(go) * tanhf2(c);
      }
      unsigned wd = (unsigned)f2bf(h2[0]) | ((unsigned)f2bf(h2[1]) << 16);
      ((unsigned*)hU)[b * 132 + Q * 32 + jp] = wd;
      astore(h1w + (size_t)(t + 1) * 1024 + b * 128 + Q * 32 + jp, wd);
    }
    fencev();
    __syncthreads();
    if (tid == 0) astore(flags + 2 + Q, (unsigned)(t + 1));
  }
}

__global__ __launch_bounds__(512, 2) void k_lstm(
    const float* __restrict__ Whh0, const float* __restrict__ Wih1,
    const float* __restrict__ Whh1, const float* __restrict__ vpn,
    const int* __restrict__ eidx, const float* __restrict__ corr,
    const float* __restrict__ inith, const float* __restrict__ initc,
    unsigned* flags, unsigned* h0w, unsigned* h1w) {
  __shared__ __align__(16) unsigned short hT[16 * 264];
  __shared__ __align__(16) unsigned short hU[16 * 264];
  __shared__ __align__(16) float gbuf[8 * 4 * 128];
  __shared__ __align__(16) float cbuf[8 * 128];
  const int tid = threadIdx.x;
  const int bx = blockIdx.x;
  if (bx == 0)
    l0_loop<0>(Whh0, vpn, eidx, corr, inith, initc, flags, h0w, hT, gbuf, cbuf, tid);
  else if (bx == 1)
    l0_loop<1>(Whh0, vpn, eidx, corr, inith, initc, flags, h0w, hT, gbuf, cbuf, tid);
  else
    l1_loop(bx - 2, Wih1, Whh1, inith, initc, flags, h0w, h1w, hT, hU, gbuf, cbuf, tid);
}

// ---- heads: 3x (256->512 relu ->1) via MFMA, then BCE + Gaussian NLL reduction ----
__global__ __launch_bounds__(256, 2) void k_heads(
    const unsigned short* __restrict__ h1u, const float* __restrict__ xadj,
    const float* __restrict__ lgW1, const float* __restrict__ lgb1,
    const float* __restrict__ lgW2, const float* __restrict__ lgb2,
    const float* __restrict__ muW1, const float* __restrict__ mub1,
    const float* __restrict__ muW2, const float* __restrict__ mub2,
    const float* __restrict__ vaW1, const float* __restrict__ vab1,
    const float* __restrict__ vaW2, const float* __restrict__ vab2,
    float* dout) {
  __shared__ float vals[4][3][64];
  const int tid = threadIdx.x;
  const int v = tid >> 6, l = tid & 63, lm = l & 15, lk = l >> 4;
  const int wid = blockIdx.x * 4 + v;
  const int m0 = wid * 64;

  short8 afr[4][8];
#pragma unroll
  for (int tt = 0; tt < 4; ++tt)
#pragma unroll
    for (int ks = 0; ks < 8; ++ks)
      afr[tt][ks] = *(const short8*)(h1u + (size_t)(m0 + tt * 16 + lm) * 256 + 2048 + ks * 32 + lk * 8);

  const float* W1s[3] = {lgW1, muW1, vaW1};
  const float* b1s[3] = {lgb1, mub1, vab1};
  const float* W2s[3] = {lgW2, muW2, vaW2};

  for (int h = 0; h < 3; ++h) {
    float accr[4][4];
#pragma unroll
    for (int tt = 0; tt < 4; ++tt)
#pragma unroll
      for (int r = 0; r < 4; ++r) accr[tt][r] = 0.f;
    const float* W1p = W1s[h];
    const float* b1p = b1s[h];
    const float* W2p = W2s[h];
    for (int nt = 0; nt < 32; ++nt) {
      float4e c0 = {0.f, 0.f, 0.f, 0.f}, c1 = c0, c2 = c0, c3 = c0;
      const float* wp = W1p + (size_t)(nt * 16 + lm) * 256;
#pragma unroll
      for (int ks = 0; ks < 8; ++ks) {
        short8 bfr = pack8f(wp + ks * 32 + lk * 8);
        c0 = MFMA16(afr[0][ks], bfr, c0);
        c1 = MFMA16(afr[1][ks], bfr, c1);
        c2 = MFMA16(afr[2][ks], bfr, c2);
        c3 = MFMA16(afr[3][ks], bfr, c3);
      }
      float bias = b1p[nt * 16 + lm], w2v = W2p[nt * 16 + lm];
#pragma unroll
      for (int r = 0; r < 4; ++r) {
        accr[0][r] += fmaxf(c0[r] + bias, 0.f) * w2v;
        accr[1][r] += fmaxf(c1[r] + bias, 0.f) * w2v;
        accr[2][r] += fmaxf(c2[r] + bias, 0.f) * w2v;
        accr[3][r] += fmaxf(c3[r] + bias, 0.f) * w2v;
      }
    }
#pragma unroll
    for (int tt = 0; tt < 4; ++tt)
#pragma unroll
      for (int r = 0; r < 4; ++r) {
        float a2 = accr[tt][r];
        a2 += __shfl_xor(a2, 1);
        a2 += __shfl_xor(a2, 2);
        a2 += __shfl_xor(a2, 4);
        a2 += __shfl_xor(a2, 8);
        if (lm == 0) vals[v][h][tt * 16 + lk * 4 + r] = a2;
      }
  }
  __syncthreads();
  {
    int m = m0 + l;
    int tq = m >> 3, b = m & 7;
    float z = vals[v][0][l] + lgb2[0];
    float mu = vals[v][1][l] + mub2[0];
    float lv = vals[v][2][l] + vab2[0];
    float x = xadj[(size_t)b * LSEQ + tq];
    float xt = (x > 0.f) ? 1.f : 0.f;
    float lr = fmaxf(z, 0.f) - z * xt + log1pf(expf(-fabsf(z)));
    float lw = 0.f;
    if (x > 0.f) {
      float sm = (x > 20.f) ? x : logf(expm1f(fminf(x, 20.f)));
      float d = mu - sm;
      lw = 0.5f * (lv + d * d * expf(-lv));
    }
#pragma unroll
    for (int d2 = 1; d2 < 64; d2 <<= 1) {
      lr += __shfl_xor(lr, d2);
      lw += __shfl_xor(lw, d2);
    }
    if (l == 0) {
      atomicAdd(dout + 0, lr * (1.f / 1024.f));
      atomicAdd(dout + 1, lw * (1.f / 1024.f));
    }
  }
}

extern "C" void kernel_launch(void* const* d_in, const int* in_sizes, int n_in,
                              void* d_out, int out_size, void* d_ws, size_t ws_size,
                              hipStream_t stream) {
  const float* x_adj = (const float*)d_in[0];
  const float* ee    = (const float*)d_in[1];
  const float* nemb  = (const float*)d_in[2];
  const float* ewW1  = (const float*)d_in[3];
  const float* ewb1  = (const float*)d_in[4];
  const float* ewW2  = (const float*)d_in[5];
  const float* ewb2  = (const float*)d_in[6];
  const float* Wih0  = (const float*)d_in[7];
  const float* Whh0  = (const float*)d_in[8];
  const float* Wih1  = (const float*)d_in[9];
  const float* Whh1  = (const float*)d_in[10];
  const float* muW1  = (const float*)d_in[11];
  const float* mub1  = (const float*)d_in[12];
  const float* muW2  = (const float*)d_in[13];
  const float* mub2  = (const float*)d_in[14];
  const float* vaW1  = (const float*)d_in[15];
  const float* vab1  = (const float*)d_in[16];
  const float* vaW2  = (const float*)d_in[17];
  const float* vab2  = (const float*)d_in[18];
  const float* lgW1  = (const float*)d_in[19];
  const float* lgb1  = (const float*)d_in[20];
  const float* lgW2  = (const float*)d_in[21];
  const float* lgb2  = (const float*)d_in[22];
  const float* inith = (const float*)d_in[23];
  const float* initc = (const float*)d_in[24];

  char* wsb = (char*)d_ws;
  unsigned* flags    = (unsigned*)wsb;            // 6 words
  unsigned* counter  = (unsigned*)(wsb + 64);
  float* P           = (float*)(wsb + WS_P);
  float* aee         = (float*)(wsb + WS_AEE);
  float* vpn         = (float*)(wsb + WS_VPN);
  int* eidx          = (int*)(wsb + WS_EIDX);
  float* corr        = (float*)(wsb + WS_CORR);
  unsigned* h0w      = (unsigned*)(wsb + WS_H0);
  unsigned* h1w      = (unsigned*)(wsb + WS_H1);
  unsigned short* h0u = (unsigned short*)(wsb + WS_H0);
  unsigned short* h1u = (unsigned short*)(wsb + WS_H1);

  (void)in_sizes; (void)n_in; (void)ws_size;

  hipMemsetAsync(d_ws, 0, 4096, stream);
  hipMemsetAsync(d_out, 0, (size_t)out_size * 4, stream);

  k_prep_P<<<512, 256, 0, stream>>>(Wih0, ewW2, P);
  k_prep_aee_init<<<8, 256, 0, stream>>>(Wih0, ee, ewb1, ewb2, P, inith, aee, h0u, h1u);
  k_prep_vpn<<<LSEQ, 256, 0, stream>>>(Wih0, nemb, aee, vpn);
  k_prep_eidx<<<(NB * LSEQ) / 256, 256, 0, stream>>>(x_adj, eidx, counter);
  k_prep_corr<<<NB * LSEQ, 256, 0, stream>>>(x_adj, ewW1, ewb1, P, aee, eidx, corr);
  k_lstm<<<6, 512, 0, stream>>>(Whh0, Wih1, Whh1, vpn, eidx, corr, inith, initc,
                                flags, h0w, h1w);
  k_heads<<<254, 256, 0, stream>>>(h1u, x_adj, lgW1, lgb1, lgW2, lgb2,
                                   muW1, mub1, muW2, mub2, vaW1, vab1, vaW2, vab2,
                                   (float*)d_out);
}